// Round 2
// baseline (1792.673 us; speedup 1.0000x reference)
//
#include <hip/hip_runtime.h>

typedef __bf16 bf16_t;
typedef __bf16 bf16x8 __attribute__((ext_vector_type(8)));
typedef float f32x4 __attribute__((ext_vector_type(4)));
typedef unsigned short u16;

#define DEV static __device__ __forceinline__

DEV float bf2f(u16 u) { __bf16 h = __builtin_bit_cast(__bf16, u); return (float)h; }
DEV u16 f2bf(float f) { __bf16 h = (__bf16)f; return __builtin_bit_cast(u16, h); }

// async global->LDS, 16B per lane; lds base must be wave-uniform.
DEV void gll16(bf16_t* lds, const bf16_t* g) {
    __builtin_amdgcn_global_load_lds(
        (const __attribute__((address_space(1))) void*)g,
        (__attribute__((address_space(3))) void*)lds, 16, 0, 0);
}

// ---------------------------------------------------------------------------
// GEMM: C[M,N] = A[M,K] * Bt[N,K]^T (+bias), bf16 in, f32 accum.
// 128x128 tile, BK=32, 4 waves, each wave 64x64 (4x4 frags of 16x16x32 MFMA).
// EPI: 0 = bf16 out (+f32 bias), 1 = bf16 out + bias + relu, 2 = f32 out * scale
// ---------------------------------------------------------------------------
template <int EPI>
__global__ __launch_bounds__(256)
void gemm_bt(const bf16_t* __restrict__ A, int lda, long sA,
             const bf16_t* __restrict__ Bt, int ldb, long sB,
             void* __restrict__ Cv, int ldc, long sC,
             const float* __restrict__ bias, int K, float scale)
{
    __shared__ bf16_t Alds[128 * 32];
    __shared__ bf16_t Blds[128 * 32];
    const int tid = threadIdx.x, w = tid >> 6, l = tid & 63;
    const int bz = blockIdx.z;
    const size_t row0 = (size_t)blockIdx.y * 128, col0 = (size_t)blockIdx.x * 128;
    A  += (size_t)bz * sA;
    Bt += (size_t)bz * sB;

    const bf16_t* Ag = A + (row0 + (size_t)(w * 32) + (l >> 2)) * lda + (l & 3) * 8;
    const bf16_t* Bg = Bt + (col0 + (size_t)(w * 32) + (l >> 2)) * ldb + (l & 3) * 8;
    bf16_t* Al = &Alds[(w * 32) * 32];
    bf16_t* Bl = &Blds[(w * 32) * 32];

    const int wm = (w >> 1) * 64, wn = (w & 1) * 64;
    f32x4 acc[4][4] = {};

    for (int k0 = 0; k0 < K; k0 += 32) {
        gll16(Al,            Ag + k0);
        gll16(Al + 16 * 32,  Ag + (size_t)16 * lda + k0);
        gll16(Bl,            Bg + k0);
        gll16(Bl + 16 * 32,  Bg + (size_t)16 * ldb + k0);
        __syncthreads();

        bf16x8 af[4], bfr[4];
#pragma unroll
        for (int i = 0; i < 4; i++) {
            af[i]  = *(const bf16x8*)&Alds[(wm + i * 16 + (l & 15)) * 32 + (l >> 4) * 8];
            bfr[i] = *(const bf16x8*)&Blds[(wn + i * 16 + (l & 15)) * 32 + (l >> 4) * 8];
        }
#pragma unroll
        for (int mi = 0; mi < 4; mi++)
#pragma unroll
            for (int ni = 0; ni < 4; ni++)
                acc[mi][ni] = __builtin_amdgcn_mfma_f32_16x16x32_bf16(af[mi], bfr[ni], acc[mi][ni], 0, 0, 0);
        __syncthreads();
    }

    const int cr = (l >> 4) * 4, cc = l & 15;
    if (EPI == 2) {
        float* C = (float*)Cv + (size_t)bz * sC;
#pragma unroll
        for (int mi = 0; mi < 4; mi++)
#pragma unroll
            for (int ni = 0; ni < 4; ni++) {
                size_t r = row0 + wm + mi * 16 + cr;
                size_t c = col0 + wn + ni * 16 + cc;
#pragma unroll
                for (int j = 0; j < 4; j++)
                    C[(r + j) * ldc + c] = acc[mi][ni][j] * scale;
            }
    } else {
        bf16_t* C = (bf16_t*)Cv + (size_t)bz * sC;
#pragma unroll
        for (int ni = 0; ni < 4; ni++) {
            size_t c = col0 + wn + ni * 16 + cc;
            float bv = bias ? bias[c] : 0.f;
#pragma unroll
            for (int mi = 0; mi < 4; mi++) {
                size_t r = row0 + wm + mi * 16 + cr;
#pragma unroll
                for (int j = 0; j < 4; j++) {
                    float v = acc[mi][ni][j] + bv;
                    if (EPI == 1) v = fmaxf(v, 0.f);
                    C[(r + j) * ldc + c] = (bf16_t)v;
                }
            }
        }
    }
}

// ---------------------------------------------------------------------------
// convert-transpose: f32 in [R][C] -> bf16 out [C][R]. grid=(C/64, R/64).
// ---------------------------------------------------------------------------
__global__ __launch_bounds__(256)
void transpose_f32_bf16(const float* __restrict__ in, bf16_t* __restrict__ out,
                        int ldin, int ldout)
{
    __shared__ bf16_t t[64][72];
    const int bx = blockIdx.x * 64;  // input col base
    const int by = blockIdx.y * 64;  // input row base
    const int tid = threadIdx.x;
    const int cj = (tid & 15) * 4, ri = tid >> 4;
#pragma unroll
    for (int k = 0; k < 4; k++) {
        int r = ri + k * 16;
        float4 v = *(const float4*)&in[(size_t)(by + r) * ldin + bx + cj];
        ushort4 o = {f2bf(v.x), f2bf(v.y), f2bf(v.z), f2bf(v.w)};
        *(ushort4*)&t[r][cj] = o;
    }
    __syncthreads();
#pragma unroll
    for (int k = 0; k < 4; k++) {
        int i = ri + k * 16;
        ushort4 o;
        o.x = __builtin_bit_cast(u16, t[cj + 0][i]);
        o.y = __builtin_bit_cast(u16, t[cj + 1][i]);
        o.z = __builtin_bit_cast(u16, t[cj + 2][i]);
        o.w = __builtin_bit_cast(u16, t[cj + 3][i]);
        *(ushort4*)&out[(size_t)(bx + i) * ldout + by + cj] = o;
    }
}

// bf16 transpose (for V): in [R][C] (ld ldin) -> out [C][R] (ld ldout)
__global__ __launch_bounds__(256)
void transpose_bf16(const bf16_t* __restrict__ in, bf16_t* __restrict__ out,
                    int ldin, int ldout, long sin_, long sout_)
{
    __shared__ bf16_t t[64][72];
    in  += (size_t)blockIdx.z * sin_;
    out += (size_t)blockIdx.z * sout_;
    const int bx = blockIdx.x * 64;
    const int by = blockIdx.y * 64;
    const int tid = threadIdx.x;
    const int cj = (tid & 15) * 4, ri = tid >> 4;
#pragma unroll
    for (int k = 0; k < 4; k++) {
        int r = ri + k * 16;
        *(ushort4*)&t[r][cj] = *(const ushort4*)&in[(size_t)(by + r) * ldin + bx + cj];
    }
    __syncthreads();
#pragma unroll
    for (int k = 0; k < 4; k++) {
        int i = ri + k * 16;
        ushort4 o;
        o.x = __builtin_bit_cast(u16, t[cj + 0][i]);
        o.y = __builtin_bit_cast(u16, t[cj + 1][i]);
        o.z = __builtin_bit_cast(u16, t[cj + 2][i]);
        o.w = __builtin_bit_cast(u16, t[cj + 3][i]);
        *(ushort4*)&out[(size_t)(bx + i) * ldout + by + cj] = o;
    }
}

// ---------------------------------------------------------------------------
// embedding (f32 table) + sinusoidal PE -> x (f32) and xb (bf16). grid = 4096.
// ---------------------------------------------------------------------------
__global__ __launch_bounds__(256)
void embed_kernel(const int* __restrict__ ids, const float* __restrict__ emb,
                  float* __restrict__ x, bf16_t* __restrict__ xb)
{
    const int row = blockIdx.x;
    const int s = row & 1023;
    const int id = ids[row];
    const float* er = emb + (size_t)id * 1024;
    float* xr = x + (size_t)row * 1024;
    bf16_t* br = xb + (size_t)row * 1024;
#pragma unroll
    for (int k = 0; k < 2; k++) {
        int i = threadIdx.x + 256 * k;  // pair index 0..511
        int d = 2 * i;
        float dv = expf((float)d * -0.008994473019508f);  // -ln(10000)/1024
        float ph = (float)s * dv;
        float sv, cv;
        sincosf(ph, &sv, &cv);
        float2 ev = *(const float2*)&er[d];
        float x0 = ev.x + sv;
        float x1 = ev.y + cv;
        float2 xo = {x0, x1};
        *(float2*)&xr[d] = xo;
        ushort2 bo = {f2bf(x0), f2bf(x1)};
        *(ushort2*)&br[d] = bo;
    }
}

// ---------------------------------------------------------------------------
// masked softmax over rows of f32 scores -> bf16 probs. One wave per row.
// ---------------------------------------------------------------------------
__global__ __launch_bounds__(256)
void softmax_kernel(const float* __restrict__ sc, const int* __restrict__ amask,
                    bf16_t* __restrict__ p)
{
    const int row = blockIdx.x * 4 + (threadIdx.x >> 6);
    const int l = threadIdx.x & 63;
    const int b = row >> 10;
    const float* s = sc + (size_t)row * 1024;
    const int* m = amask + (size_t)b * 1024;
    float v[16];
    float mx = -3.0e38f;
#pragma unroll
    for (int i = 0; i < 4; i++) {
        int c = 4 * l + 256 * i;
        float4 sv = *(const float4*)&s[c];
        int4 mv = *(const int4*)&m[c];
        v[4 * i + 0] = mv.x ? sv.x : -1e9f;
        v[4 * i + 1] = mv.y ? sv.y : -1e9f;
        v[4 * i + 2] = mv.z ? sv.z : -1e9f;
        v[4 * i + 3] = mv.w ? sv.w : -1e9f;
        mx = fmaxf(mx, fmaxf(fmaxf(v[4 * i], v[4 * i + 1]), fmaxf(v[4 * i + 2], v[4 * i + 3])));
    }
#pragma unroll
    for (int o = 32; o; o >>= 1) mx = fmaxf(mx, __shfl_xor(mx, o, 64));
    float sum = 0.f;
#pragma unroll
    for (int i = 0; i < 16; i++) { v[i] = __expf(v[i] - mx); sum += v[i]; }
#pragma unroll
    for (int o = 32; o; o >>= 1) sum += __shfl_xor(sum, o, 64);
    float inv = 1.0f / sum;
#pragma unroll
    for (int i = 0; i < 4; i++) {
        int c = 4 * l + 256 * i;
        ushort4 st;
        st.x = f2bf(v[4 * i + 0] * inv);
        st.y = f2bf(v[4 * i + 1] * inv);
        st.z = f2bf(v[4 * i + 2] * inv);
        st.w = f2bf(v[4 * i + 3] * inv);
        *(ushort4*)&p[(size_t)row * 1024 + c] = st;
    }
}

// ---------------------------------------------------------------------------
// residual + LayerNorm: t = xin + add; y = LN(t)*g + beta (g,beta f32)
// writes y to xout (f32) and bout (bf16). grid = 4096 rows, 256 threads.
// ---------------------------------------------------------------------------
__global__ __launch_bounds__(256)
void ln_kernel(const float* __restrict__ xin, const bf16_t* __restrict__ add,
               const float* __restrict__ g, const float* __restrict__ beta,
               float* __restrict__ xout, bf16_t* __restrict__ bout)
{
    __shared__ float red[8];
    const int row = blockIdx.x;
    const int t = threadIdx.x;
    const size_t base = (size_t)row * 1024 + t * 4;
    float4 xv = *(const float4*)&xin[base];
    ushort4 au = *(const ushort4*)&add[base];
    float tv[4];
    tv[0] = xv.x + bf2f(au.x);
    tv[1] = xv.y + bf2f(au.y);
    tv[2] = xv.z + bf2f(au.z);
    tv[3] = xv.w + bf2f(au.w);
    float s = tv[0] + tv[1] + tv[2] + tv[3];
    float s2 = tv[0] * tv[0] + tv[1] * tv[1] + tv[2] * tv[2] + tv[3] * tv[3];
#pragma unroll
    for (int o = 32; o; o >>= 1) { s += __shfl_xor(s, o, 64); s2 += __shfl_xor(s2, o, 64); }
    if ((t & 63) == 0) { red[t >> 6] = s; red[4 + (t >> 6)] = s2; }
    __syncthreads();
    s = red[0] + red[1] + red[2] + red[3];
    s2 = red[4] + red[5] + red[6] + red[7];
    const float mu = s * (1.f / 1024.f);
    const float var = s2 * (1.f / 1024.f) - mu * mu;
    const float rs = rsqrtf(var + 1e-5f);
    float4 gu = *(const float4*)&g[t * 4];
    float4 bu = *(const float4*)&beta[t * 4];
    float y0 = (tv[0] - mu) * rs * gu.x + bu.x;
    float y1 = (tv[1] - mu) * rs * gu.y + bu.y;
    float y2 = (tv[2] - mu) * rs * gu.z + bu.z;
    float y3 = (tv[3] - mu) * rs * gu.w + bu.w;
    float4 yo = {y0, y1, y2, y3};
    *(float4*)&xout[base] = yo;
    ushort4 ob = {f2bf(y0), f2bf(y1), f2bf(y2), f2bf(y3)};
    *(ushort4*)&bout[base] = ob;
}

__global__ __launch_bounds__(256)
void biascat_kernel(const float* __restrict__ bq, const float* __restrict__ bk,
                    const float* __restrict__ bv, float* __restrict__ o)
{
    int i = blockIdx.x * 256 + threadIdx.x;  // 0..3071
    o[i] = (i < 1024) ? bq[i] : (i < 2048) ? bk[i - 1024] : bv[i - 2048];
}

// ---------------------------------------------------------------------------

extern "C" void kernel_launch(void* const* d_in, const int* in_sizes, int n_in,
                              void* d_out, int out_size, void* d_ws, size_t ws_size,
                              hipStream_t stream)
{
    const int*   ids = (const int*)d_in[0];
    const int*   am  = (const int*)d_in[1];
    const float* emb = (const float*)d_in[2];
    const float* Wq  = (const float*)d_in[3];
    const float* Wk  = (const float*)d_in[4];
    const float* Wv  = (const float*)d_in[5];
    const float* bq  = (const float*)d_in[6];
    const float* bk  = (const float*)d_in[7];
    const float* bv  = (const float*)d_in[8];
    const float* g1  = (const float*)d_in[9];
    const float* be1 = (const float*)d_in[10];
    const float* Wf1 = (const float*)d_in[11];
    const float* bf1 = (const float*)d_in[12];
    const float* Wf2 = (const float*)d_in[13];
    const float* bf2_ = (const float*)d_in[14];
    const float* g2  = (const float*)d_in[15];
    const float* be2 = (const float*)d_in[16];

    char* ws = (char*)d_ws;
    float*  x      = (float*)(ws);                      // 16 MB  [0,16M)
    bf16_t* xb     = (bf16_t*)(ws + (16LL << 20));      // 8 MB   [16,24)
    bf16_t* qkv    = (bf16_t*)(ws + (24LL << 20));      // 24 MB  [24,48)
    bf16_t* vt     = (bf16_t*)(ws + (48LL << 20));      // 8 MB   [48,56)
    float*  scores = (float*)(ws + (56LL << 20));       // 16 MB  [56,72)  (aliases h)
    bf16_t* p      = (bf16_t*)(ws + (72LL << 20));      // 8 MB   [72,80)  (aliases h)
    bf16_t* h      = (bf16_t*)(ws + (56LL << 20));      // 32 MB  [56,88)
    bf16_t* attn   = (bf16_t*)(ws + (88LL << 20));      // 8 MB   [88,96)  (also f)
    bf16_t* wqkvT  = (bf16_t*)(ws + (96LL << 20));      // 6 MB   [96,102)
    bf16_t* wf1T   = (bf16_t*)(ws + (102LL << 20));     // 8 MB   [102,110)
    bf16_t* wf2T   = (bf16_t*)(ws + (110LL << 20));     // 8 MB   [110,118)
    float*  qbias  = (float*)(ws + (118LL << 20));      // 12 KB

    embed_kernel<<<4096, 256, 0, stream>>>(ids, emb, x, xb);

    for (int l = 0; l < 6; l++) {
        const size_t DD = 1024 * 1024;
        // weight convert-transposes: f32 [K][N] -> bf16 [N][K]
        transpose_f32_bf16<<<dim3(16, 16, 1), 256, 0, stream>>>(Wq + (size_t)l * DD, wqkvT,          1024, 1024);
        transpose_f32_bf16<<<dim3(16, 16, 1), 256, 0, stream>>>(Wk + (size_t)l * DD, wqkvT + DD,     1024, 1024);
        transpose_f32_bf16<<<dim3(16, 16, 1), 256, 0, stream>>>(Wv + (size_t)l * DD, wqkvT + 2 * DD, 1024, 1024);
        transpose_f32_bf16<<<dim3(64, 16, 1), 256, 0, stream>>>(Wf1 + (size_t)l * 4 * DD, wf1T, 4096, 1024);
        transpose_f32_bf16<<<dim3(16, 64, 1), 256, 0, stream>>>(Wf2 + (size_t)l * 4 * DD, wf2T, 1024, 4096);
        biascat_kernel<<<12, 256, 0, stream>>>(bq + l * 1024, bk + l * 1024, bv + l * 1024, qbias);

        // fused QKV: [4096,1024] x [3072,1024]^T -> qkv [4096,3072]
        gemm_bt<0><<<dim3(24, 32, 1), 256, 0, stream>>>(xb, 1024, 0, wqkvT, 1024, 0,
                                                        qkv, 3072, 0, qbias, 1024, 0.f);
        // V^T per batch: [S,D] (ld 3072) -> [D,S]
        transpose_bf16<<<dim3(16, 16, 4), 256, 0, stream>>>(qkv + 2048, vt, 3072, 1024,
                                                            1024L * 3072, 1024L * 1024);
        // scores = Q K^T * 1/32  (f32)
        gemm_bt<2><<<dim3(8, 8, 4), 256, 0, stream>>>(qkv, 3072, 1024L * 3072,
                                                      qkv + 1024, 3072, 1024L * 3072,
                                                      scores, 1024, 1024L * 1024,
                                                      nullptr, 1024, 0.03125f);
        softmax_kernel<<<1024, 256, 0, stream>>>(scores, am, p);
        // attn = P V  (via V^T as Bt)
        gemm_bt<0><<<dim3(8, 8, 4), 256, 0, stream>>>(p, 1024, 1024L * 1024,
                                                      vt, 1024, 1024L * 1024,
                                                      attn, 1024, 1024L * 1024,
                                                      nullptr, 1024, 0.f);
        ln_kernel<<<4096, 256, 0, stream>>>(x, attn, g1 + l * 1024, be1 + l * 1024, x, xb);
        // FF1 with relu -> h [4096,4096]
        gemm_bt<1><<<dim3(32, 32, 1), 256, 0, stream>>>(xb, 1024, 0, wf1T, 1024, 0,
                                                        h, 4096, 0, bf1 + l * 4096, 1024, 0.f);
        // FF2 -> f (reuse attn buffer) [4096,1024]
        gemm_bt<0><<<dim3(8, 32, 1), 256, 0, stream>>>(h, 4096, 0, wf2T, 4096, 0,
                                                       attn, 1024, 0, bf2_ + l * 1024, 4096, 0.f);
        float*  xo = (l == 5) ? (float*)d_out : x;
        ln_kernel<<<4096, 256, 0, stream>>>(x, attn, g2 + l * 1024, be2 + l * 1024, xo, xb);
    }
    (void)in_sizes; (void)n_in; (void)out_size; (void)ws_size;
}

// Round 3
// 1538.187 us; speedup vs baseline: 1.1654x; 1.1654x over previous
//
#include <hip/hip_runtime.h>

typedef __bf16 bf16_t;
typedef __bf16 bf16x8 __attribute__((ext_vector_type(8)));
typedef float f32x4 __attribute__((ext_vector_type(4)));
typedef unsigned short u16;

#define DEV static __device__ __forceinline__

DEV float bf2f(u16 u) { __bf16 h = __builtin_bit_cast(__bf16, u); return (float)h; }
DEV u16 f2bf(float f) { __bf16 h = (__bf16)f; return __builtin_bit_cast(u16, h); }

// async global->LDS, 16B per lane; lds base must be wave-uniform.
DEV void gll16(bf16_t* lds, const bf16_t* g) {
    __builtin_amdgcn_global_load_lds(
        (const __attribute__((address_space(1))) void*)g,
        (__attribute__((address_space(3))) void*)lds, 16, 0, 0);
}

// ---------------------------------------------------------------------------
// GEMM: C[M,N] = A[M,K] * Bt[N,K]^T (+bias), bf16 in, f32 accum.
// 128x128 tile, BK=64, 4 waves, each wave 64x64 (4x4 frags of 16x16x32 MFMA).
// LDS tiles [128][64] with st-style XOR swizzle: LDS slot s of row r holds
// global 16B-slot s^(r&7); achieved by pre-swizzling the per-lane GLOBAL
// source (global_load_lds writes linearly) and XOR-ing on the ds_read side.
// Within each quarter-wave the read hits each 16B slot exactly twice -> free.
// EPI: 0 = bf16 out (+f32 bias), 1 = bf16 out + bias + relu, 2 = f32 out * scale
// ---------------------------------------------------------------------------
template <int EPI>
__global__ __launch_bounds__(256)
void gemm_bt(const bf16_t* __restrict__ A, int lda, long sA,
             const bf16_t* __restrict__ Bt, int ldb, long sB,
             void* __restrict__ Cv, int ldc, long sC,
             const float* __restrict__ bias, int K, float scale)
{
    __shared__ bf16_t Alds[128 * 64];
    __shared__ bf16_t Blds[128 * 64];
    const int tid = threadIdx.x, w = tid >> 6, l = tid & 63;
    const int bz = blockIdx.z;
    const size_t row0 = (size_t)blockIdx.y * 128, col0 = (size_t)blockIdx.x * 128;
    A  += (size_t)bz * sA;
    Bt += (size_t)bz * sB;

    const int lr = l >> 3;            // row within an 8-row chunk
    const int sl = (l & 7) ^ lr;      // pre-swizzled source 16B-slot
    const bf16_t* Ag = A  + (row0 + (size_t)(w * 32) + lr) * lda + sl * 8;
    const bf16_t* Bg = Bt + (col0 + (size_t)(w * 32) + lr) * ldb + sl * 8;
    bf16_t* Al = &Alds[(w * 32) * 64];
    bf16_t* Bl = &Blds[(w * 32) * 64];

    const int wm = (w >> 1) * 64, wn = (w & 1) * 64;
    f32x4 acc[4][4] = {};

    for (int k0 = 0; k0 < K; k0 += 64) {
#pragma unroll
        for (int c = 0; c < 4; c++) {
            gll16(Al + c * 8 * 64, Ag + (size_t)(c * 8) * lda + k0);
            gll16(Bl + c * 8 * 64, Bg + (size_t)(c * 8) * ldb + k0);
        }
        __syncthreads();

#pragma unroll
        for (int ks = 0; ks < 2; ks++) {
            bf16x8 afr[4], bfr[4];
#pragma unroll
            for (int i = 0; i < 4; i++) {
                const int fr = i * 16 + (l & 15);
                const int slot = (ks * 4 + (l >> 4)) ^ (l & 7);  // (l&7) == row&7
                afr[i] = *(const bf16x8*)&Alds[(wm + fr) * 64 + slot * 8];
                bfr[i] = *(const bf16x8*)&Blds[(wn + fr) * 64 + slot * 8];
            }
#pragma unroll
            for (int mi = 0; mi < 4; mi++)
#pragma unroll
                for (int ni = 0; ni < 4; ni++)
                    acc[mi][ni] = __builtin_amdgcn_mfma_f32_16x16x32_bf16(afr[mi], bfr[ni], acc[mi][ni], 0, 0, 0);
        }
        __syncthreads();
    }

    const int cr = (l >> 4) * 4, cc = l & 15;
    if (EPI == 2) {
        float* C = (float*)Cv + (size_t)bz * sC;
#pragma unroll
        for (int mi = 0; mi < 4; mi++)
#pragma unroll
            for (int ni = 0; ni < 4; ni++) {
                size_t r = row0 + wm + mi * 16 + cr;
                size_t c = col0 + wn + ni * 16 + cc;
#pragma unroll
                for (int j = 0; j < 4; j++)
                    C[(r + j) * ldc + c] = acc[mi][ni][j] * scale;
            }
    } else {
        bf16_t* C = (bf16_t*)Cv + (size_t)bz * sC;
#pragma unroll
        for (int ni = 0; ni < 4; ni++) {
            size_t c = col0 + wn + ni * 16 + cc;
            float bv = bias ? bias[c] : 0.f;
#pragma unroll
            for (int mi = 0; mi < 4; mi++) {
                size_t r = row0 + wm + mi * 16 + cr;
#pragma unroll
                for (int j = 0; j < 4; j++) {
                    float v = acc[mi][ni][j] + bv;
                    if (EPI == 1) v = fmaxf(v, 0.f);
                    C[(r + j) * ldc + c] = (bf16_t)v;
                }
            }
        }
    }
}

// ---------------------------------------------------------------------------
// convert-transpose: f32 in [R][C] -> bf16 out [C][R]. grid=(C/64, R/64).
// ---------------------------------------------------------------------------
__global__ __launch_bounds__(256)
void transpose_f32_bf16(const float* __restrict__ in, bf16_t* __restrict__ out,
                        int ldin, int ldout)
{
    __shared__ bf16_t t[64][72];
    const int bx = blockIdx.x * 64;  // input col base
    const int by = blockIdx.y * 64;  // input row base
    const int tid = threadIdx.x;
    const int cj = (tid & 15) * 4, ri = tid >> 4;
#pragma unroll
    for (int k = 0; k < 4; k++) {
        int r = ri + k * 16;
        float4 v = *(const float4*)&in[(size_t)(by + r) * ldin + bx + cj];
        ushort4 o = {f2bf(v.x), f2bf(v.y), f2bf(v.z), f2bf(v.w)};
        *(ushort4*)&t[r][cj] = o;
    }
    __syncthreads();
#pragma unroll
    for (int k = 0; k < 4; k++) {
        int i = ri + k * 16;
        ushort4 o;
        o.x = __builtin_bit_cast(u16, t[cj + 0][i]);
        o.y = __builtin_bit_cast(u16, t[cj + 1][i]);
        o.z = __builtin_bit_cast(u16, t[cj + 2][i]);
        o.w = __builtin_bit_cast(u16, t[cj + 3][i]);
        *(ushort4*)&out[(size_t)(bx + i) * ldout + by + cj] = o;
    }
}

// bf16 transpose (for V): in [R][C] (ld ldin) -> out [C][R] (ld ldout)
__global__ __launch_bounds__(256)
void transpose_bf16(const bf16_t* __restrict__ in, bf16_t* __restrict__ out,
                    int ldin, int ldout, long sin_, long sout_)
{
    __shared__ bf16_t t[64][72];
    in  += (size_t)blockIdx.z * sin_;
    out += (size_t)blockIdx.z * sout_;
    const int bx = blockIdx.x * 64;
    const int by = blockIdx.y * 64;
    const int tid = threadIdx.x;
    const int cj = (tid & 15) * 4, ri = tid >> 4;
#pragma unroll
    for (int k = 0; k < 4; k++) {
        int r = ri + k * 16;
        *(ushort4*)&t[r][cj] = *(const ushort4*)&in[(size_t)(by + r) * ldin + bx + cj];
    }
    __syncthreads();
#pragma unroll
    for (int k = 0; k < 4; k++) {
        int i = ri + k * 16;
        ushort4 o;
        o.x = __builtin_bit_cast(u16, t[cj + 0][i]);
        o.y = __builtin_bit_cast(u16, t[cj + 1][i]);
        o.z = __builtin_bit_cast(u16, t[cj + 2][i]);
        o.w = __builtin_bit_cast(u16, t[cj + 3][i]);
        *(ushort4*)&out[(size_t)(bx + i) * ldout + by + cj] = o;
    }
}

// ---------------------------------------------------------------------------
// embedding (f32 table) + sinusoidal PE -> x (f32) and xb (bf16). grid = 4096.
// ---------------------------------------------------------------------------
__global__ __launch_bounds__(256)
void embed_kernel(const int* __restrict__ ids, const float* __restrict__ emb,
                  float* __restrict__ x, bf16_t* __restrict__ xb)
{
    const int row = blockIdx.x;
    const int s = row & 1023;
    const int id = ids[row];
    const float* er = emb + (size_t)id * 1024;
    float* xr = x + (size_t)row * 1024;
    bf16_t* br = xb + (size_t)row * 1024;
#pragma unroll
    for (int k = 0; k < 2; k++) {
        int i = threadIdx.x + 256 * k;  // pair index 0..511
        int d = 2 * i;
        float dv = expf((float)d * -0.008994473019508f);  // -ln(10000)/1024
        float ph = (float)s * dv;
        float sv, cv;
        sincosf(ph, &sv, &cv);
        float2 ev = *(const float2*)&er[d];
        float x0 = ev.x + sv;
        float x1 = ev.y + cv;
        float2 xo = {x0, x1};
        *(float2*)&xr[d] = xo;
        ushort2 bo = {f2bf(x0), f2bf(x1)};
        *(ushort2*)&br[d] = bo;
    }
}

// ---------------------------------------------------------------------------
// masked softmax over rows of f32 scores -> bf16 probs. One wave per row.
// ---------------------------------------------------------------------------
__global__ __launch_bounds__(256)
void softmax_kernel(const float* __restrict__ sc, const int* __restrict__ amask,
                    bf16_t* __restrict__ p)
{
    const int row = blockIdx.x * 4 + (threadIdx.x >> 6);
    const int l = threadIdx.x & 63;
    const int b = row >> 10;
    const float* s = sc + (size_t)row * 1024;
    const int* m = amask + (size_t)b * 1024;
    float v[16];
    float mx = -3.0e38f;
#pragma unroll
    for (int i = 0; i < 4; i++) {
        int c = 4 * l + 256 * i;
        float4 sv = *(const float4*)&s[c];
        int4 mv = *(const int4*)&m[c];
        v[4 * i + 0] = mv.x ? sv.x : -1e9f;
        v[4 * i + 1] = mv.y ? sv.y : -1e9f;
        v[4 * i + 2] = mv.z ? sv.z : -1e9f;
        v[4 * i + 3] = mv.w ? sv.w : -1e9f;
        mx = fmaxf(mx, fmaxf(fmaxf(v[4 * i], v[4 * i + 1]), fmaxf(v[4 * i + 2], v[4 * i + 3])));
    }
#pragma unroll
    for (int o = 32; o; o >>= 1) mx = fmaxf(mx, __shfl_xor(mx, o, 64));
    float sum = 0.f;
#pragma unroll
    for (int i = 0; i < 16; i++) { v[i] = __expf(v[i] - mx); sum += v[i]; }
#pragma unroll
    for (int o = 32; o; o >>= 1) sum += __shfl_xor(sum, o, 64);
    float inv = 1.0f / sum;
#pragma unroll
    for (int i = 0; i < 4; i++) {
        int c = 4 * l + 256 * i;
        ushort4 st;
        st.x = f2bf(v[4 * i + 0] * inv);
        st.y = f2bf(v[4 * i + 1] * inv);
        st.z = f2bf(v[4 * i + 2] * inv);
        st.w = f2bf(v[4 * i + 3] * inv);
        *(ushort4*)&p[(size_t)row * 1024 + c] = st;
    }
}

// ---------------------------------------------------------------------------
// residual + LayerNorm: t = xin + add; y = LN(t)*g + beta (g,beta f32)
// writes y to xout (f32) and bout (bf16). grid = 4096 rows, 256 threads.
// ---------------------------------------------------------------------------
__global__ __launch_bounds__(256)
void ln_kernel(const float* __restrict__ xin, const bf16_t* __restrict__ add,
               const float* __restrict__ g, const float* __restrict__ beta,
               float* __restrict__ xout, bf16_t* __restrict__ bout)
{
    __shared__ float red[8];
    const int row = blockIdx.x;
    const int t = threadIdx.x;
    const size_t base = (size_t)row * 1024 + t * 4;
    float4 xv = *(const float4*)&xin[base];
    ushort4 au = *(const ushort4*)&add[base];
    float tv[4];
    tv[0] = xv.x + bf2f(au.x);
    tv[1] = xv.y + bf2f(au.y);
    tv[2] = xv.z + bf2f(au.z);
    tv[3] = xv.w + bf2f(au.w);
    float s = tv[0] + tv[1] + tv[2] + tv[3];
    float s2 = tv[0] * tv[0] + tv[1] * tv[1] + tv[2] * tv[2] + tv[3] * tv[3];
#pragma unroll
    for (int o = 32; o; o >>= 1) { s += __shfl_xor(s, o, 64); s2 += __shfl_xor(s2, o, 64); }
    if ((t & 63) == 0) { red[t >> 6] = s; red[4 + (t >> 6)] = s2; }
    __syncthreads();
    s = red[0] + red[1] + red[2] + red[3];
    s2 = red[4] + red[5] + red[6] + red[7];
    const float mu = s * (1.f / 1024.f);
    const float var = s2 * (1.f / 1024.f) - mu * mu;
    const float rs = rsqrtf(var + 1e-5f);
    float4 gu = *(const float4*)&g[t * 4];
    float4 bu = *(const float4*)&beta[t * 4];
    float y0 = (tv[0] - mu) * rs * gu.x + bu.x;
    float y1 = (tv[1] - mu) * rs * gu.y + bu.y;
    float y2 = (tv[2] - mu) * rs * gu.z + bu.z;
    float y3 = (tv[3] - mu) * rs * gu.w + bu.w;
    float4 yo = {y0, y1, y2, y3};
    *(float4*)&xout[base] = yo;
    ushort4 ob = {f2bf(y0), f2bf(y1), f2bf(y2), f2bf(y3)};
    *(ushort4*)&bout[base] = ob;
}

__global__ __launch_bounds__(256)
void biascat_kernel(const float* __restrict__ bq, const float* __restrict__ bk,
                    const float* __restrict__ bv, float* __restrict__ o)
{
    int i = blockIdx.x * 256 + threadIdx.x;  // 0..3071
    o[i] = (i < 1024) ? bq[i] : (i < 2048) ? bk[i - 1024] : bv[i - 2048];
}

// ---------------------------------------------------------------------------

extern "C" void kernel_launch(void* const* d_in, const int* in_sizes, int n_in,
                              void* d_out, int out_size, void* d_ws, size_t ws_size,
                              hipStream_t stream)
{
    const int*   ids = (const int*)d_in[0];
    const int*   am  = (const int*)d_in[1];
    const float* emb = (const float*)d_in[2];
    const float* Wq  = (const float*)d_in[3];
    const float* Wk  = (const float*)d_in[4];
    const float* Wv  = (const float*)d_in[5];
    const float* bq  = (const float*)d_in[6];
    const float* bk  = (const float*)d_in[7];
    const float* bv  = (const float*)d_in[8];
    const float* g1  = (const float*)d_in[9];
    const float* be1 = (const float*)d_in[10];
    const float* Wf1 = (const float*)d_in[11];
    const float* bf1 = (const float*)d_in[12];
    const float* Wf2 = (const float*)d_in[13];
    const float* bf2_ = (const float*)d_in[14];
    const float* g2  = (const float*)d_in[15];
    const float* be2 = (const float*)d_in[16];

    char* ws = (char*)d_ws;
    float*  x      = (float*)(ws);                      // 16 MB  [0,16M)
    bf16_t* xb     = (bf16_t*)(ws + (16LL << 20));      // 8 MB   [16,24)
    bf16_t* qkv    = (bf16_t*)(ws + (24LL << 20));      // 24 MB  [24,48)
    bf16_t* vt     = (bf16_t*)(ws + (48LL << 20));      // 8 MB   [48,56)
    float*  scores = (float*)(ws + (56LL << 20));       // 16 MB  [56,72)  (aliases h)
    bf16_t* p      = (bf16_t*)(ws + (72LL << 20));      // 8 MB   [72,80)  (aliases h)
    bf16_t* h      = (bf16_t*)(ws + (56LL << 20));      // 32 MB  [56,88)
    bf16_t* attn   = (bf16_t*)(ws + (88LL << 20));      // 8 MB   [88,96)  (also f)
    bf16_t* wqkvT  = (bf16_t*)(ws + (96LL << 20));      // 6 MB   [96,102)
    bf16_t* wf1T   = (bf16_t*)(ws + (102LL << 20));     // 8 MB   [102,110)
    bf16_t* wf2T   = (bf16_t*)(ws + (110LL << 20));     // 8 MB   [110,118)
    float*  qbias  = (float*)(ws + (118LL << 20));      // 12 KB

    embed_kernel<<<4096, 256, 0, stream>>>(ids, emb, x, xb);

    for (int l = 0; l < 6; l++) {
        const size_t DD = 1024 * 1024;
        // weight convert-transposes: f32 [K][N] -> bf16 [N][K]
        transpose_f32_bf16<<<dim3(16, 16, 1), 256, 0, stream>>>(Wq + (size_t)l * DD, wqkvT,          1024, 1024);
        transpose_f32_bf16<<<dim3(16, 16, 1), 256, 0, stream>>>(Wk + (size_t)l * DD, wqkvT + DD,     1024, 1024);
        transpose_f32_bf16<<<dim3(16, 16, 1), 256, 0, stream>>>(Wv + (size_t)l * DD, wqkvT + 2 * DD, 1024, 1024);
        transpose_f32_bf16<<<dim3(64, 16, 1), 256, 0, stream>>>(Wf1 + (size_t)l * 4 * DD, wf1T, 4096, 1024);
        transpose_f32_bf16<<<dim3(16, 64, 1), 256, 0, stream>>>(Wf2 + (size_t)l * 4 * DD, wf2T, 1024, 4096);
        biascat_kernel<<<12, 256, 0, stream>>>(bq + l * 1024, bk + l * 1024, bv + l * 1024, qbias);

        // fused QKV: [4096,1024] x [3072,1024]^T -> qkv [4096,3072]
        gemm_bt<0><<<dim3(24, 32, 1), 256, 0, stream>>>(xb, 1024, 0, wqkvT, 1024, 0,
                                                        qkv, 3072, 0, qbias, 1024, 0.f);
        // V^T per batch: [S,D] (ld 3072) -> [D,S]
        transpose_bf16<<<dim3(16, 16, 4), 256, 0, stream>>>(qkv + 2048, vt, 3072, 1024,
                                                            1024L * 3072, 1024L * 1024);
        // scores = Q K^T * 1/32  (f32)
        gemm_bt<2><<<dim3(8, 8, 4), 256, 0, stream>>>(qkv, 3072, 1024L * 3072,
                                                      qkv + 1024, 3072, 1024L * 3072,
                                                      scores, 1024, 1024L * 1024,
                                                      nullptr, 1024, 0.03125f);
        softmax_kernel<<<1024, 256, 0, stream>>>(scores, am, p);
        // attn = P V  (via V^T as Bt)
        gemm_bt<0><<<dim3(8, 8, 4), 256, 0, stream>>>(p, 1024, 1024L * 1024,
                                                      vt, 1024, 1024L * 1024,
                                                      attn, 1024, 1024L * 1024,
                                                      nullptr, 1024, 0.f);
        ln_kernel<<<4096, 256, 0, stream>>>(x, attn, g1 + l * 1024, be1 + l * 1024, x, xb);
        // FF1 with relu -> h [4096,4096]
        gemm_bt<1><<<dim3(32, 32, 1), 256, 0, stream>>>(xb, 1024, 0, wf1T, 1024, 0,
                                                        h, 4096, 0, bf1 + l * 4096, 1024, 0.f);
        // FF2 -> f (reuse attn buffer) [4096,1024]
        gemm_bt<0><<<dim3(8, 32, 1), 256, 0, stream>>>(h, 4096, 0, wf2T, 4096, 0,
                                                       attn, 1024, 0, bf2_ + l * 1024, 4096, 0.f);
        float*  xo = (l == 5) ? (float*)d_out : x;
        ln_kernel<<<4096, 256, 0, stream>>>(x, attn, g2 + l * 1024, be2 + l * 1024, xo, xb);
    }
    (void)in_sizes; (void)n_in; (void)out_size; (void)ws_size;
}